// Round 9
// baseline (279.938 us; speedup 1.0000x reference)
//
#include <hip/hip_runtime.h>
#include <cstdint>
#include <cstddef>

#define T_LEN 8192
#define BATCH 64
#define HID   10
#define CH    66
#define EEG   64
#define SM_STRIDE 8384   // 192-entry zero pad + 8192 live, per batch (16B-aligned stride)

// ---------------------------------------------------------------------------
// K1: front projection (SPLIT BACK OUT for attribution — round-8 decision).
// y[b][h][t] = b_front[h] + sum_c x[b,0,c+1,t]*w_front[h,c]
// grid (8, 64), block 256, 4 t per thread (float4 loads, float4 stores).
// One bit-exact change vs round-0: wf padded to [64][12] and fetched as
// float4+float4+float2 (3 ds_reads/channel instead of 10 broadcasts); FMA
// order over (c, h, j) unchanged -> y bit-identical. out-zero folded in.
// ---------------------------------------------------------------------------
__global__ void k_front(const float* __restrict__ x, const float* __restrict__ wf_g,
                        const float* __restrict__ bf_g, float* __restrict__ y,
                        float* __restrict__ out) {
    __shared__ float wf[EEG][12];    // wf[c][h], h-padded to 12 (48B rows, 16B-aligned)
    __shared__ float bf[HID];
    int tid = threadIdx.x;
    for (int i = tid; i < EEG * 12; i += 256) {
        int c = i / 12, h = i - 12 * (i / 12);
        wf[c][h] = (h < HID) ? wf_g[h * EEG + c] : 0.f;   // w_front layout (H, C)
    }
    if (tid < HID) bf[tid] = bf_g[tid];
    if (blockIdx.x == 0 && blockIdx.y == 0)   // fold out-memset (runs before k_lsnn)
        for (int i = tid; i < BATCH * 2; i += 256) out[i] = 0.f;
    __syncthreads();

    int b = blockIdx.y;
    int t4 = (blockIdx.x * 256 + tid) * 4;
    const float* xb = x + ((size_t)b * CH + 1) * T_LEN + t4;   // skip aud channel 0
    float acc[4][HID];
#pragma unroll
    for (int j = 0; j < 4; ++j)
#pragma unroll
        for (int h = 0; h < HID; ++h) acc[j][h] = bf[h];
#pragma unroll 4
    for (int c = 0; c < EEG; ++c) {
        float4 xv = *(const float4*)(xb + (size_t)c * T_LEN);
        float4 w0 = *(const float4*)&wf[c][0];
        float4 w1 = *(const float4*)&wf[c][4];
        float2 w2 = *(const float2*)&wf[c][8];
        float w[HID] = {w0.x, w0.y, w0.z, w0.w, w1.x, w1.y, w1.z, w1.w, w2.x, w2.y};
#pragma unroll
        for (int h = 0; h < HID; ++h) {
            acc[0][h] = fmaf(xv.x, w[h], acc[0][h]);
            acc[1][h] = fmaf(xv.y, w[h], acc[1][h]);
            acc[2][h] = fmaf(xv.z, w[h], acc[2][h]);
            acc[3][h] = fmaf(xv.w, w[h], acc[3][h]);
        }
    }
    float* yo = y + (size_t)b * HID * T_LEN + t4;   // [b][h][t]: lane-consecutive t4
#pragma unroll
    for (int h = 0; h < HID; ++h)
        *(float4*)(yo + (size_t)h * T_LEN) =
            make_float4(acc[0][h], acc[1][h], acc[2][h], acc[3][h]);
}

// ---------------------------------------------------------------------------
// K2: front LIF (round-2 verified version, verbatim). 128 chunks of 64 live
// steps, warm 32 (0.25^32 ~ 5e-20). grid 2048 -> 8 waves/CU, 3-deep float4
// prefetch ring, writer-XCD-aligned chunk mapping. Chunk-0 blocks zero the
// 192-entry smask pad.
// ---------------------------------------------------------------------------
__global__ __launch_bounds__(64) void k_flif(const float* __restrict__ y,
                                             unsigned short* __restrict__ smask) {
    int id = blockIdx.x;
    int c  = (id & 7) * 16 + ((id >> 3) & 15);  // chunk 0..127; id%8 == c>>4 (writer XCD)
    int bq = id >> 7;                            // batch quad 0..15
    int lane = threadIdx.x;
    int g = lane >> 4, h = lane & 15;
    int b = bq * 4 + g;
    int hh = h < HID ? h : HID - 1;  // inactive lanes duplicate h=9 (bits masked later)

    if (c == 0) {                    // zero the pad region for this block's 4 batches
        for (int i = lane; i < 4 * 96; i += 64) {
            int j = i / 96, w = i % 96;
            ((unsigned*)(smask + (size_t)(bq * 4 + j) * SM_STRIDE))[w] = 0u;
        }
    }

    int t0 = c * 64;
    int ts = t0 - 32; if (ts < 0) ts = 0;
    int nf = (t0 + 64 - ts) >> 2;   // # float4 steps (16 for c=0, else 24)
    const float4* yb = (const float4*)(y + ((size_t)b * HID + hh) * T_LEN + ts);

    float4 A = yb[0], B = yb[1], C = yb[2];
    float u = 0.f, o = 0.f;
    unsigned short* smb = smask + (size_t)b * SM_STRIDE + 192;
    for (int f = 0; f < nf; ++f) {
        int nx = f + 3; if (nx > nf - 1) nx = nf - 1;
        float4 D = yb[nx];
        float vv[4] = {A.x, A.y, A.z, A.w};
        int tb = ts + f * 4;
#pragma unroll
        for (int k = 0; k < 4; ++k) {
            u = (o > 0.5f) ? vv[k] : fmaf(0.25f, u, vv[k]);   // 0.25*u exact
            bool sp = (u > 0.2f);
            o = sp ? 1.0f : 0.0f;
            unsigned long long bal = __ballot(sp);
            int t = tb + k;
            if (t >= t0 && h == 0)
                smb[t] = (unsigned short)((bal >> (g * 16)) & 0x3FFull);
        }
        A = B; B = C; C = D;
    }
}

// ---------------------------------------------------------------------------
// K3: LSNN scan + classifier. 128 chunks x 64 live steps, warm 192 (zero pad
// -> uniform 256-step loop). Direct 1024x22 subset-sum table D (88 KB LDS):
// every rec/X/P lookup is a single ds_read_b32. Unchanged (verified).
// ---------------------------------------------------------------------------
__global__ __launch_bounds__(512) void k_lsnn(
    const unsigned short* __restrict__ smask,
    const float* __restrict__ w_in, const float* __restrict__ w_rec,
    const float* __restrict__ w_cls, const float* __restrict__ b_cls,
    float* __restrict__ out) {
    extern __shared__ float LDSBUF[];
    float* T = LDSBUF;          // [1536]: [hi*768 + m*24 + role]
    float* D = LDSBUF + 1536;   // [1024*22]: full 10-bit subset sums
    int tid = threadIdx.x;
    for (int i = tid; i < 1536; i += 512) {
        int hi = i / 768;
        int rem = i - hi * 768;
        int m = rem / 24, role = rem - m * 24;
        float s = 0.f;
        if (role < 22) {
            const float* wrow = (role < 10) ? (w_in + role * HID)
                              : (role < 12) ? (w_cls + (role - 10) * HID)
                                            : (w_rec + (role - 12) * HID);
#pragma unroll
            for (int j = 0; j < 5; ++j)
                if (m & (1u << j)) s += wrow[hi * 5 + j];
        }
        T[i] = s;
    }
    __syncthreads();
    for (int i = tid; i < 1024 * 22; i += 512) {
        int z = i / 22, role = i - z * 22;
        D[i] = T[(z & 31) * 24 + role] + T[768 + (z >> 5) * 24 + role];
    }
    __syncthreads();

    int lane = tid & 63;
    int q = lane >> 4;                 // unit-in-wave 0..3
    int r = lane & 15;                 // role: 0..9 hidden, 10..11 cls, 12..15 shadow
    int rr = r < 12 ? r : 11;          // X/P table role (shadows duplicate 11)
    int rrec = 12 + (r < HID ? r : 9); // rec table role
    int shq = q * 16;
    int id = blockIdx.x * 32 + (tid >> 4);   // 256*32 = 8192 units, no tail
    int b = id >> 7, chunk = id & 127;

    float bcl = (r == 10 || r == 11) ? b_cls[r - HID] : 0.f;

    const unsigned short* sm = smask + (size_t)b * SM_STRIDE + (size_t)chunk * 64;

    auto xlook = [&](const uint4& mv, float* X) {
        unsigned hw[8] = { mv.x & 0x3FFu, (mv.x >> 16) & 0x3FFu,
                           mv.y & 0x3FFu, (mv.y >> 16) & 0x3FFu,
                           mv.z & 0x3FFu, (mv.z >> 16) & 0x3FFu,
                           mv.w & 0x3FFu, (mv.w >> 16) & 0x3FFu };
#pragma unroll
        for (int u = 0; u < 8; ++u)
            X[u] = D[hw[u] * 22 + rr];
    };

    // 4-deep mask prefetch ring
    uint4 mB = *(const uint4*)(sm + 8);
    uint4 mC = *(const uint4*)(sm + 16);
    uint4 mD = *(const uint4*)(sm + 24);
    float Xc[8], Xn[8], Pc[8], Pn[8];
    { uint4 m0 = *(const uint4*)(sm); xlook(m0, Xc); }
#pragma unroll
    for (int u = 0; u < 8; ++u) { Pc[u] = 0.f; Pn[u] = 0.f; }

    float v = 0.f, cur = 0.f;
    unsigned zmask = 0;
    float uc = 0.f, oc = 0.f, accs = 0.f;

    for (int gr = 0; gr < 32; ++gr) {
        int nb = gr + 4; if (nb > 31) nb = 31;
        uint4 mE = *(const uint4*)(sm + (size_t)nb * 8);
        xlook(mB, Xn);                  // x_in for next group (off-chain)
        unsigned zs[8];
#pragma unroll
        for (int u = 0; u < 8; ++u) {
            float rec = D[zmask * 22 + rrec];
            float ij = (cur + Xc[u]) + rec;
            float vd = v + 0.1f * (ij - v);     // bit-exact form
            cur = ij - 0.2f * ij;               // bit-exact form
            bool zb = vd > 0.2f;                // b_dec == VTH exactly
            unsigned long long bal = __ballot(zb);
            v = zb ? 0.f : vd;
            zmask = (unsigned)(bal >> shq) & 0x3FFu;
            zs[u] = zmask;
        }
        if (gr >= 21) {                        // classifier-input lookups
#pragma unroll
            for (int u = 0; u < 8; ++u)
                Pn[u] = D[zs[u] * 22 + rr];
        }
        if (gr >= 22) {                        // classifier LIF for group gr-1
            bool in = (gr >= 25);              // live groups are 24..31
#pragma unroll
            for (int u = 0; u < 8; ++u) {
                float ci = Pc[u] + bcl;
                uc = (oc > 0.5f) ? ci : fmaf(0.25f, uc, ci);
                oc = (uc > 0.2f) ? 1.f : 0.f;
                if (in) accs += oc;
            }
        }
#pragma unroll
        for (int u = 0; u < 8; ++u) { Xc[u] = Xn[u]; Pc[u] = Pn[u]; }
        mB = mC; mC = mD; mD = mE;
    }
    // epilogue: classifier for group 31 (live)
#pragma unroll
    for (int u = 0; u < 8; ++u) {
        float ci = Pc[u] + bcl;
        uc = (oc > 0.5f) ? ci : fmaf(0.25f, uc, ci);
        oc = (uc > 0.2f) ? 1.f : 0.f;
        accs += oc;
    }
    if (r == 10 || r == 11)
        atomicAdd(&out[b * 2 + (r - 10)], accs * (1.0f / 8192.0f));
}

// ---------------------------------------------------------------------------
extern "C" void kernel_launch(void* const* d_in, const int* in_sizes, int n_in,
                              void* d_out, int out_size, void* d_ws, size_t ws_size,
                              hipStream_t stream) {
    const float* x       = (const float*)d_in[0];
    const float* w_front = (const float*)d_in[1];
    const float* b_front = (const float*)d_in[2];
    const float* w_in    = (const float*)d_in[3];
    const float* w_rec   = (const float*)d_in[4];
    const float* w_cls   = (const float*)d_in[5];
    const float* b_cls   = (const float*)d_in[6];
    float* out = (float*)d_out;

    float* y = (float*)d_ws;                                   // 20 MB, [b][h][t]
    unsigned short* smask =
        (unsigned short*)((char*)d_ws + (size_t)BATCH * HID * T_LEN * sizeof(float));

    k_front<<<dim3(T_LEN / 1024, BATCH), 256, 0, stream>>>(x, w_front, b_front, y, out);
    k_flif<<<dim3(2048), 64, 0, stream>>>(y, smask);
    k_lsnn<<<dim3(256), 512, (1536 + 1024 * 22) * sizeof(float), stream>>>(
        smask, w_in, w_rec, w_cls, b_cls, out);
}

// Round 11
// 271.602 us; speedup vs baseline: 1.0307x; 1.0307x over previous
//
#include <hip/hip_runtime.h>
#include <cstdint>
#include <cstddef>

#define T_LEN 8192
#define BATCH 64
#define HID   10
#define CH    66
#define EEG   64
#define SM_STRIDE 8384   // 192-entry zero pad + 8192 live, per batch (16B-aligned stride)

// ---------------------------------------------------------------------------
// K1: front projection, v6 — BURST-LENGTH experiment.
// Evidence r5/r7/r8: occupancy (8->16 waves), VGPR prefetch depth, and DMA
// staging ALL leave k_front at ~80 us / ~900 GB/s. The untouched invariant:
// every variant reads x in <=4 KB bursts with 32 KB jumps (c-stride) --
// short bursts defeat L2 prefetch, exposing miss latency against a finite
// per-CU miss budget (~3.5 GB/s/CU observed). Fills (linear) hit 6.9 TB/s.
// This version doubles the burst: block = (b, t-quarter 2048) x 512 thr,
// per c-step the block reads 8 KB CONTIGUOUS before the jump. grid (4,64)
// = 256 blocks = 1/CU, 8 waves/CU, ring-4 prefetch (static idx, ~100 VGPR).
// Per-(t,h) chain ascending-c from bf -> y BIT-IDENTICAL to all rounds.
// ---------------------------------------------------------------------------
__global__ __launch_bounds__(512) void k_front(
    const float* __restrict__ x, const float* __restrict__ wf_g,
    const float* __restrict__ bf_g, float* __restrict__ y,
    float* __restrict__ out) {
    __shared__ float wf[EEG][12];    // wf[c][h], h-padded to 12 (48B rows)
    __shared__ float bf[HID];
    int tid = threadIdx.x;
    for (int i = tid; i < EEG * 12; i += 512) {
        int c = i / 12, h = i - 12 * (i / 12);
        wf[c][h] = (h < HID) ? wf_g[h * EEG + c] : 0.f;   // w_front layout (H, C)
    }
    if (tid < HID) bf[tid] = bf_g[tid];
    if (blockIdx.x == 0 && blockIdx.y == 0)   // fold out-memset (runs before k_lsnn)
        for (int i = tid; i < BATCH * 2; i += 512) out[i] = 0.f;
    __syncthreads();

    int b  = blockIdx.y;
    int t4 = blockIdx.x * 2048 + tid * 4;     // t-quarter; 512 thr x 4 t = 2048
    const float* xb = x + ((size_t)b * CH + 1) * T_LEN + t4;   // skip aud channel 0

    float4 ring[4];                           // 4-deep c-prefetch ring (static idx)
#pragma unroll
    for (int j = 0; j < 4; ++j) ring[j] = *(const float4*)(xb + (size_t)j * T_LEN);

    float acc[4][HID];
#pragma unroll
    for (int j = 0; j < 4; ++j)
#pragma unroll
        for (int h = 0; h < HID; ++h) acc[j][h] = bf[h];

#pragma unroll 4
    for (int c = 0; c < EEG; ++c) {
        float4 xv = ring[c & 3];
        if (c + 4 < EEG)                      // compile-time under unroll 4
            ring[c & 3] = *(const float4*)(xb + (size_t)(c + 4) * T_LEN);
        float4 w0 = *(const float4*)&wf[c][0];
        float4 w1 = *(const float4*)&wf[c][4];
        float2 w2 = *(const float2*)&wf[c][8];
        float w[HID] = {w0.x, w0.y, w0.z, w0.w, w1.x, w1.y, w1.z, w1.w, w2.x, w2.y};
#pragma unroll
        for (int h = 0; h < HID; ++h) {
            acc[0][h] = fmaf(xv.x, w[h], acc[0][h]);
            acc[1][h] = fmaf(xv.y, w[h], acc[1][h]);
            acc[2][h] = fmaf(xv.z, w[h], acc[2][h]);
            acc[3][h] = fmaf(xv.w, w[h], acc[3][h]);
        }
    }
    float* yo = y + (size_t)b * HID * T_LEN + t4;   // [b][h][t]
#pragma unroll
    for (int h = 0; h < HID; ++h)
        *(float4*)(yo + (size_t)h * T_LEN) =
            make_float4(acc[0][h], acc[1][h], acc[2][h], acc[3][h]);
}

// ---------------------------------------------------------------------------
// K2: front LIF (round-2 verified version). 128 chunks of 64 live steps,
// warm 32. grid 2048 -> 8 waves/CU, 3-deep float4 prefetch ring. Chunk-0
// blocks zero the 192-entry smask pad. Unchanged for attribution.
// ---------------------------------------------------------------------------
__global__ __launch_bounds__(64) void k_flif(const float* __restrict__ y,
                                             unsigned short* __restrict__ smask) {
    int id = blockIdx.x;
    int c  = (id & 7) * 16 + ((id >> 3) & 15);  // chunk 0..127
    int bq = id >> 7;                            // batch quad 0..15
    int lane = threadIdx.x;
    int g = lane >> 4, h = lane & 15;
    int b = bq * 4 + g;
    int hh = h < HID ? h : HID - 1;  // inactive lanes duplicate h=9 (bits masked later)

    if (c == 0) {                    // zero the pad region for this block's 4 batches
        for (int i = lane; i < 4 * 96; i += 64) {
            int j = i / 96, w = i % 96;
            ((unsigned*)(smask + (size_t)(bq * 4 + j) * SM_STRIDE))[w] = 0u;
        }
    }

    int t0 = c * 64;
    int ts = t0 - 32; if (ts < 0) ts = 0;
    int nf = (t0 + 64 - ts) >> 2;   // # float4 steps (16 for c=0, else 24)
    const float4* yb = (const float4*)(y + ((size_t)b * HID + hh) * T_LEN + ts);

    float4 A = yb[0], B = yb[1], C = yb[2];
    float u = 0.f, o = 0.f;
    unsigned short* smb = smask + (size_t)b * SM_STRIDE + 192;
    for (int f = 0; f < nf; ++f) {
        int nx = f + 3; if (nx > nf - 1) nx = nf - 1;
        float4 D = yb[nx];
        float vv[4] = {A.x, A.y, A.z, A.w};
        int tb = ts + f * 4;
#pragma unroll
        for (int k = 0; k < 4; ++k) {
            u = (o > 0.5f) ? vv[k] : fmaf(0.25f, u, vv[k]);   // 0.25*u exact
            bool sp = (u > 0.2f);
            o = sp ? 1.0f : 0.0f;
            unsigned long long bal = __ballot(sp);
            int t = tb + k;
            if (t >= t0 && h == 0)
                smb[t] = (unsigned short)((bal >> (g * 16)) & 0x3FFull);
        }
        A = B; B = C; C = D;
    }
}

// ---------------------------------------------------------------------------
// K3: LSNN scan + classifier. Direct 1024x22 subset-sum table D (88 KB LDS):
// every rec/X/P lookup is a single ds_read_b32. Unchanged (verified).
// ---------------------------------------------------------------------------
__global__ __launch_bounds__(512) void k_lsnn(
    const unsigned short* __restrict__ smask,
    const float* __restrict__ w_in, const float* __restrict__ w_rec,
    const float* __restrict__ w_cls, const float* __restrict__ b_cls,
    float* __restrict__ out) {
    extern __shared__ float LDSBUF[];
    float* T = LDSBUF;          // [1536]: [hi*768 + m*24 + role]
    float* D = LDSBUF + 1536;   // [1024*22]: full 10-bit subset sums
    int tid = threadIdx.x;
    for (int i = tid; i < 1536; i += 512) {
        int hi = i / 768;
        int rem = i - hi * 768;
        int m = rem / 24, role = rem - m * 24;
        float s = 0.f;
        if (role < 22) {
            const float* wrow = (role < 10) ? (w_in + role * HID)
                              : (role < 12) ? (w_cls + (role - 10) * HID)
                                            : (w_rec + (role - 12) * HID);
#pragma unroll
            for (int j = 0; j < 5; ++j)
                if (m & (1u << j)) s += wrow[hi * 5 + j];
        }
        T[i] = s;
    }
    __syncthreads();
    for (int i = tid; i < 1024 * 22; i += 512) {
        int z = i / 22, role = i - z * 22;
        D[i] = T[(z & 31) * 24 + role] + T[768 + (z >> 5) * 24 + role];
    }
    __syncthreads();

    int lane = tid & 63;
    int q = lane >> 4;                 // unit-in-wave 0..3
    int r = lane & 15;                 // role: 0..9 hidden, 10..11 cls, 12..15 shadow
    int rr = r < 12 ? r : 11;          // X/P table role (shadows duplicate 11)
    int rrec = 12 + (r < HID ? r : 9); // rec table role
    int shq = q * 16;
    int id = blockIdx.x * 32 + (tid >> 4);   // 256*32 = 8192 units, no tail
    int b = id >> 7, chunk = id & 127;

    float bcl = (r == 10 || r == 11) ? b_cls[r - HID] : 0.f;

    const unsigned short* sm = smask + (size_t)b * SM_STRIDE + (size_t)chunk * 64;

    auto xlook = [&](const uint4& mv, float* X) {
        unsigned hw[8] = { mv.x & 0x3FFu, (mv.x >> 16) & 0x3FFu,
                           mv.y & 0x3FFu, (mv.y >> 16) & 0x3FFu,
                           mv.z & 0x3FFu, (mv.z >> 16) & 0x3FFu,
                           mv.w & 0x3FFu, (mv.w >> 16) & 0x3FFu };
#pragma unroll
        for (int u = 0; u < 8; ++u)
            X[u] = D[hw[u] * 22 + rr];
    };

    // 4-deep mask prefetch ring
    uint4 mB = *(const uint4*)(sm + 8);
    uint4 mC = *(const uint4*)(sm + 16);
    uint4 mD = *(const uint4*)(sm + 24);
    float Xc[8], Xn[8], Pc[8], Pn[8];
    { uint4 m0 = *(const uint4*)(sm); xlook(m0, Xc); }
#pragma unroll
    for (int u = 0; u < 8; ++u) { Pc[u] = 0.f; Pn[u] = 0.f; }

    float v = 0.f, cur = 0.f;
    unsigned zmask = 0;
    float uc = 0.f, oc = 0.f, accs = 0.f;

    for (int gr = 0; gr < 32; ++gr) {
        int nb = gr + 4; if (nb > 31) nb = 31;
        uint4 mE = *(const uint4*)(sm + (size_t)nb * 8);
        xlook(mB, Xn);                  // x_in for next group (off-chain)
        unsigned zs[8];
#pragma unroll
        for (int u = 0; u < 8; ++u) {
            float rec = D[zmask * 22 + rrec];
            float ij = (cur + Xc[u]) + rec;
            float vd = v + 0.1f * (ij - v);     // bit-exact form
            cur = ij - 0.2f * ij;               // bit-exact form
            bool zb = vd > 0.2f;                // b_dec == VTH exactly
            unsigned long long bal = __ballot(zb);
            v = zb ? 0.f : vd;
            zmask = (unsigned)(bal >> shq) & 0x3FFu;
            zs[u] = zmask;
        }
        if (gr >= 21) {                        // classifier-input lookups
#pragma unroll
            for (int u = 0; u < 8; ++u)
                Pn[u] = D[zs[u] * 22 + rr];
        }
        if (gr >= 22) {                        // classifier LIF for group gr-1
            bool in = (gr >= 25);              // live groups are 24..31
#pragma unroll
            for (int u = 0; u < 8; ++u) {
                float ci = Pc[u] + bcl;
                uc = (oc > 0.5f) ? ci : fmaf(0.25f, uc, ci);
                oc = (uc > 0.2f) ? 1.f : 0.f;
                if (in) accs += oc;
            }
        }
#pragma unroll
        for (int u = 0; u < 8; ++u) { Xc[u] = Xn[u]; Pc[u] = Pn[u]; }
        mB = mC; mC = mD; mD = mE;
    }
    // epilogue: classifier for group 31 (live)
#pragma unroll
    for (int u = 0; u < 8; ++u) {
        float ci = Pc[u] + bcl;
        uc = (oc > 0.5f) ? ci : fmaf(0.25f, uc, ci);
        oc = (uc > 0.2f) ? 1.f : 0.f;
        accs += oc;
    }
    if (r == 10 || r == 11)
        atomicAdd(&out[b * 2 + (r - 10)], accs * (1.0f / 8192.0f));
}

// ---------------------------------------------------------------------------
extern "C" void kernel_launch(void* const* d_in, const int* in_sizes, int n_in,
                              void* d_out, int out_size, void* d_ws, size_t ws_size,
                              hipStream_t stream) {
    const float* x       = (const float*)d_in[0];
    const float* w_front = (const float*)d_in[1];
    const float* b_front = (const float*)d_in[2];
    const float* w_in    = (const float*)d_in[3];
    const float* w_rec   = (const float*)d_in[4];
    const float* w_cls   = (const float*)d_in[5];
    const float* b_cls   = (const float*)d_in[6];
    float* out = (float*)d_out;

    float* y = (float*)d_ws;                                   // 20 MB, [b][h][t]
    unsigned short* smask =
        (unsigned short*)((char*)d_ws + (size_t)BATCH * HID * T_LEN * sizeof(float));

    k_front<<<dim3(4, BATCH), 512, 0, stream>>>(x, w_front, b_front, y, out);
    k_flif<<<dim3(2048), 64, 0, stream>>>(y, smask);
    k_lsnn<<<dim3(256), 512, (1536 + 1024 * 22) * sizeof(float), stream>>>(
        smask, w_in, w_rec, w_cls, b_cls, out);
}